// Round 2
// baseline (321.378 us; speedup 1.0000x reference)
//
#include <hip/hip_runtime.h>
#include <math.h>

#define N_TOK 131072
#define N_E   1024
#define E_DIM 64
#define BETA  0.4

// d_out layout (float32, concatenated in return order):
#define ZQ_OFF   0
#define LOSS_OFF 8388608
#define IDX_OFF  8388609
#define PERP_OFF 8519681

// d_ws layout (round-2 pass proved ws_size >= 532492; we use 338 KB):
#define WS_C2    0        // 1024 f32: RN32(exact ||c_e||^2)
#define WS_CNT   4096     // 1024 i32 counts
#define WS_SSQ   8192     // double sum_sq
#define WS_WLC   8200     // int worklist count (+4 pad)
#define WS_C2H   8208     // 2048 B: fp16(-512*c2)
#define WS_FH    10256    // 131072 B: fp16(codebook * 1024), MFMA B-frag layout
#define WS_WL    141328   // 16384 ints: worklist (flagged token ids)
#define WS_KEYS  206864   // 16384 u64: packed (d_bits<<32)|e per worklist slot
#define WLCAP    16384

typedef _Float16 f16x8 __attribute__((ext_vector_type(8)));
typedef float f32x4  __attribute__((ext_vector_type(4)));
typedef unsigned long long u64;

__device__ __forceinline__ void gl2lds16(const void* g, void* l) {
    __builtin_amdgcn_global_load_lds(
        (const __attribute__((address_space(1))) unsigned int*)g,
        (__attribute__((address_space(3))) unsigned int*)l, 16, 0, 0);
}

// Codebook -> fp16 MFMA B-fragment layout, scaled by 1024 (exact pow2) to keep
// all magnitudes >> fp16 denormal range. Also: exact-f32 c2 + fp16(-512*c2),
// counts/wlc/sum_sq zero-init, keys init.
__global__ void frag_kernel(const float* __restrict__ cb,
                            unsigned short* __restrict__ fh,
                            u64* __restrict__ keys,
                            float* __restrict__ c2,
                            unsigned short* __restrict__ c2h,
                            int* __restrict__ counts, int* __restrict__ wlc,
                            double* __restrict__ sum_sq) {
    int tid = blockIdx.x * 256 + threadIdx.x;   // 65536 total
    if (tid < WLCAP) keys[tid] = ~0ull;
    if (tid < N_E) {
        const float* p = cb + (size_t)tid * E_DIM;
        double s = 0.0;
#pragma unroll
        for (int k = 0; k < E_DIM; ++k) {
            double c = (double)p[k];
            s = fma(c, c, s);
        }
        float c2f = (float)s;
        c2[tid] = c2f;
        union { _Float16 h; unsigned short u; } q;
        q.h = (_Float16)(-512.0f * c2f);        // exact pow2 scale, then RN
        c2h[tid] = q.u;
        counts[tid] = 0;
        if (tid == 0) { *wlc = 0; *sum_sq = 0.0; }
    }
    int j  = tid & 7;
    int l  = (tid >> 3) & 63;
    int cc = tid >> 9;
    int code = (cc >> 1) * 16 + (l & 15);
    int k    = (cc & 1) * 32 + (l >> 4) * 8 + j;
    float f = cb[(size_t)code * E_DIM + k] * 1024.0f;  // exact pow2 scale
    union { _Float16 h; unsigned short s; } cv;
    cv.h = (_Float16)f;                                 // RN f32->f16
    fh[tid] = cv.s;
}

// Cold path (worklist overflow only). Exact numpy-f32 semantics, serial.
__device__ __attribute__((noinline)) int exact_best_serial(
    const float* __restrict__ z, const float* __restrict__ cb,
    const float* __restrict__ c2, int n) {
    const float* zr = z + (size_t)n * E_DIM;
    float r[8];
#pragma unroll
    for (int j = 0; j < 8; ++j) r[j] = __fmul_rn(zr[j], zr[j]);
#pragma unroll 1
    for (int i = 8; i < 64; i += 8)
#pragma unroll
        for (int j = 0; j < 8; ++j)
            r[j] = __fadd_rn(r[j], __fmul_rn(zr[i + j], zr[i + j]));
    float z2 = __fadd_rn(__fadd_rn(__fadd_rn(r[0], r[1]), __fadd_rn(r[2], r[3])),
                         __fadd_rn(__fadd_rn(r[4], r[5]), __fadd_rn(r[6], r[7])));
    u64 bestkey = ~0ull;
#pragma unroll 1
    for (int e = 0; e < N_E; ++e) {
        const float* cp = cb + (size_t)e * E_DIM;
        double m = 0.0;
#pragma unroll 1
        for (int i = 0; i < E_DIM; ++i)
            m = fma((double)zr[i], (double)cp[i], m);
        float d = __fsub_rn(__fadd_rn(z2, c2[e]), __fmul_rn(2.0f, (float)m));
        u64 key = ((u64)__float_as_uint(d) << 32) | (unsigned)e;
        if (key < bestkey) bestkey = key;
    }
    return (int)(bestkey & 0xffffffffu);
}

// Screen: 2048 blocks x 64 tokens, 8 blocks/CU (32 waves/CU = 100% occupancy).
// fp16 single-product screen; error covered by margin 0.07 (validated round 1)
// + exact fixup. 16 stages x 64 codes, 8 KB double-buffered staging, single
// barrier per stage. Track max of u'' = 1024*dot - 512*c2 + 64 (> 0),
// key = (bits&~63)|(63-c).
__global__ __launch_bounds__(256, 8) void vq_main(
    const float* __restrict__ z, const float* __restrict__ cb,
    const float* __restrict__ c2, const unsigned short* __restrict__ c2h_,
    const unsigned short* __restrict__ fh_,
    int* __restrict__ counts, double* __restrict__ sum_sq,
    int* __restrict__ wl_count, int* __restrict__ wl, float margin_u,
    float* __restrict__ out) {

    __shared__ unsigned char stagebuf[2][8192];   // double-buffered fp16 stage
    __shared__ __align__(8) unsigned short c2s[N_E];  // fp16(-512*c2)
    __shared__ int   best_s[64];
    __shared__ unsigned char flag_s[64];
    __shared__ double wred[4];

    const int tid  = threadIdx.x;
    const int lane = tid & 63;
    const int wid  = tid >> 6;
    const int col  = lane & 15;
    const int quad = lane >> 4;
    const int blk_tok0 = blockIdx.x * 64;
    const int wave_tok0 = blk_tok0 + wid * 16;

    const char* hsrc0 = (const char*)fh_;
    auto stage = [&](int s, int b) {
#pragma unroll
        for (int i = 0; i < 2; ++i)
            gl2lds16(hsrc0 + s * 8192 + i * 4096 + tid * 16,
                     &stagebuf[b][i * 4096 + wid * 1024]);
    };

    stage(0, 0);   // issue codebook staging first; overlaps z loads below

    ((uint2*)c2s)[tid] = ((const uint2*)c2h_)[tid];   // 256 x 8 B = 2 KB

    // A fragments: 1 tile x 2 k-chunks, fp16 (z unscaled; |z|<~6 fits fp16)
    f16x8 Ah[2];
    {
        const float* zr = z + (size_t)(wave_tok0 + col) * E_DIM + quad * 8;
#pragma unroll
        for (int kc = 0; kc < 2; ++kc) {
            float4 u0 = *(const float4*)(zr + kc * 32);
            float4 u1 = *(const float4*)(zr + kc * 32 + 4);
            f16x8 a;
            a[0] = (_Float16)u0.x; a[1] = (_Float16)u0.y;
            a[2] = (_Float16)u0.z; a[3] = (_Float16)u0.w;
            a[4] = (_Float16)u1.x; a[5] = (_Float16)u1.y;
            a[6] = (_Float16)u1.z; a[7] = (_Float16)u1.w;
            Ah[kc] = a;
        }
    }

    // packed-key top-2 MAX tracker
    unsigned k1[4], k2[4];
#pragma unroll
    for (int r = 0; r < 4; ++r) { k1[r] = 0u; k2[r] = 0u; }

    for (int s = 0; s < 16; ++s) {
        __syncthreads();              // drains vmcnt -> staged data for s ready
        if (s + 1 < 16) stage(s + 1, (s + 1) & 1);
        const unsigned char* hb = &stagebuf[s & 1][0];
#pragma unroll
        for (int cl = 0; cl < 4; ++cl) {
            const int c = s * 4 + cl;
            const int off0 = cl * 2048 + lane * 16;
            union { uint4 u; f16x8 v; } b0, b1;
            b0.u = *(const uint4*)(hb + off0);
            b1.u = *(const uint4*)(hb + off0 + 1024);
            union { unsigned short us; _Float16 h; } cv;
            cv.us = c2s[c * 16 + col];
            const float ch = 64.0f + (float)cv.h;
            const f32x4 cinit = {ch, ch, ch, ch};
            const unsigned ctag = (unsigned)(63 - c);
            f32x4 acc = __builtin_amdgcn_mfma_f32_16x16x32_f16(
                Ah[0], b0.v, cinit, 0, 0, 0);
            acc = __builtin_amdgcn_mfma_f32_16x16x32_f16(
                Ah[1], b1.v, acc, 0, 0, 0);
#pragma unroll
            for (int r = 0; r < 4; ++r) {
                unsigned key = (__float_as_uint(acc[r]) & 0xFFFFFFC0u) | ctag;
                unsigned hi2 = min(k1[r], key);
                k2[r] = max(k2[r], hi2);
                k1[r] = max(k1[r], key);
            }
        }
    }

    // merge + decide, per r: maximize u'', tie -> lowest code index
#pragma unroll
    for (int r = 0; r < 4; ++r) {
        float v1 = __uint_as_float(k1[r] & 0xFFFFFFC0u);
        float v2 = __uint_as_float(k2[r] & 0xFFFFFFC0u);
        int   b1 = (63 - (int)(k1[r] & 63u)) * 16 + col;
#pragma unroll
        for (int d = 1; d < 16; d <<= 1) {
            float o1 = __shfl_xor(v1, d, 64);
            float o2 = __shfl_xor(v2, d, 64);
            int   ob = __shfl_xor(b1, d, 64);
            float n2 = fmaxf(fmaxf(v2, o2), fminf(v1, o1));
            bool take = (o1 > v1) || (o1 == v1 && ob < b1);
            v1 = fmaxf(v1, o1);
            b1 = take ? ob : b1;
            v2 = n2;
        }
        if (col == 0) {
            int tl = wid * 16 + quad * 4 + r;
            int n  = blk_tok0 + tl;
            int best = b1;
            bool fl = (v1 - v2) < margin_u;
            if (fl) {
                int pos = atomicAdd(wl_count, 1);
                if (pos < WLCAP) wl[pos] = n;
                else { best = exact_best_serial(z, cb, c2, n); fl = false; }
            }
            best_s[tl] = best;
            flag_s[tl] = fl ? 1 : 0;
            if (!fl) atomicAdd(&counts[best], 1);
        }
    }
    __syncthreads();

    // coalesced idx write (flagged slots overwritten later by fixup_apply)
    if (tid < 64) out[IDX_OFF + blk_tok0 + tid] = (float)best_s[tid];

    // epilogue: coalesced z_q / loss for unflagged tokens (exact f32 z re-read)
    const int sub = tid & 15, grp = tid >> 4;
    double dl = 0.0;
    const float4* zrow = (const float4*)z;
    const float4* crow = (const float4*)cb;
    float4* qrow = (float4*)(out + ZQ_OFF);
#pragma unroll
    for (int p = 0; p < 4; ++p) {
        int tl = p * 16 + grp;
        if (!flag_s[tl]) {
            int n = blk_tok0 + tl;
            float4 z4 = zrow[(size_t)n * 16 + sub];
            float4 c4 = crow[(size_t)best_s[tl] * 16 + sub];
            float dx = c4.x - z4.x, dy = c4.y - z4.y;
            float dz = c4.z - z4.z, dw = c4.w - z4.w;
            float4 q;
            q.x = z4.x + dx; q.y = z4.y + dy;
            q.z = z4.z + dz; q.w = z4.w + dw;
            qrow[(size_t)n * 16 + sub] = q;
            dl += (double)dx * dx + (double)dy * dy
                + (double)dz * dz + (double)dw * dw;
        }
    }
#pragma unroll
    for (int off = 32; off > 0; off >>= 1)
        dl += __shfl_down(dl, off, 64);
    if (lane == 0) wred[wid] = dl;
    __syncthreads();
    if (tid == 0)
        atomicAdd(sum_sq, wred[0] + wred[1] + wred[2] + wred[3]);
}

// Scan: one wave per (64-token group x 32-code slice); token-per-lane,
// wave-uniform cb rows. z2 (numpy pairwise) computed inline from exact z.
__global__ __launch_bounds__(64) void fixup_scan(
    const float* __restrict__ z, const float* __restrict__ cb,
    const float* __restrict__ c2, const int* __restrict__ wl,
    const int* __restrict__ wl_count, u64* __restrict__ keys) {

    int count = *wl_count; if (count > WLCAP) count = WLCAP;
    const int g = blockIdx.x >> 5;        // token group (64 per group)
    const int s = blockIdx.x & 31;        // code slice (32 codes)
    if (g * 64 >= count) return;
    const int lane = threadIdx.x;
    const int w = g * 64 + lane;
    const bool valid = w < count;
    const int n = wl[valid ? w : g * 64];

    double zd[E_DIM];
    const float4* zp = (const float4*)(z + (size_t)n * E_DIM);
#pragma unroll
    for (int k = 0; k < 16; ++k) {
        float4 v = zp[k];
        zd[4 * k]     = (double)v.x;
        zd[4 * k + 1] = (double)v.y;
        zd[4 * k + 2] = (double)v.z;
        zd[4 * k + 3] = (double)v.w;
    }
    // numpy-pairwise z2 in f32 (8 accumulators + tree); (float)zd is exact
    float r8[8];
#pragma unroll
    for (int j = 0; j < 8; ++j) {
        float f = (float)zd[j];
        r8[j] = __fmul_rn(f, f);
    }
#pragma unroll
    for (int i = 8; i < 64; i += 8)
#pragma unroll
        for (int j = 0; j < 8; ++j) {
            float f = (float)zd[i + j];
            r8[j] = __fadd_rn(r8[j], __fmul_rn(f, f));
        }
    const float z2 = __fadd_rn(
        __fadd_rn(__fadd_rn(r8[0], r8[1]), __fadd_rn(r8[2], r8[3])),
        __fadd_rn(__fadd_rn(r8[4], r8[5]), __fadd_rn(r8[6], r8[7])));

    u64 best = ~0ull;
    const int e0 = s * 32;
#pragma unroll 2
    for (int e = e0; e < e0 + 32; ++e) {
        const float* cp = cb + (size_t)e * E_DIM;   // wave-uniform row
        double m = 0.0;
#pragma unroll
        for (int i = 0; i < E_DIM; ++i)
            m = fma(zd[i], (double)cp[i], m);
        float d = __fsub_rn(__fadd_rn(z2, c2[e]), __fmul_rn(2.0f, (float)m));
        u64 key = ((u64)__float_as_uint(d) << 32) | (unsigned)e;
        if (key < best) best = key;
    }
    if (valid) atomicMin(&keys[w], best);
}

// Apply: one wave per worklist token; finish zq/idx/counts/sum_sq.
__global__ __launch_bounds__(256) void fixup_apply(
    const float* __restrict__ z, const float* __restrict__ cb,
    const int* __restrict__ wl, const int* __restrict__ wl_count,
    const u64* __restrict__ keys, int* __restrict__ counts,
    double* __restrict__ sum_sq, float* __restrict__ out) {

    int count = *wl_count; if (count > WLCAP) count = WLCAP;
    const int lane = threadIdx.x & 63;
    const int gw = blockIdx.x * 4 + (threadIdx.x >> 6);
    for (int w = gw; w < count; w += 1024) {
        const int n = wl[w];
        const int best = (int)(keys[w] & 0xffffffffull);
        float cv = cb[(size_t)best * E_DIM + lane];
        float zi = z[(size_t)n * E_DIM + lane];
        float diff = cv - zi;
        out[ZQ_OFF + (size_t)n * E_DIM + lane] = zi + diff;
        double d2 = (double)diff * (double)diff;
#pragma unroll
        for (int off = 32; off > 0; off >>= 1)
            d2 += __shfl_down(d2, off, 64);
        if (lane == 0) {
            atomicAdd(sum_sq, d2);
            atomicAdd(&counts[best], 1);
            out[IDX_OFF + n] = (float)best;
        }
    }
}

__global__ __launch_bounds__(1024) void finalize_kernel(
    const int* __restrict__ counts, const double* __restrict__ sum_sq,
    float* __restrict__ out) {
    __shared__ double red[1024];
    int e = threadIdx.x;
    double em = (double)counts[e] / (double)N_TOK;
    red[e] = -em * log(em + 1e-10);
    __syncthreads();
    for (int s = 512; s > 0; s >>= 1) {
        if (e < s) red[e] += red[e + s];
        __syncthreads();
    }
    if (e == 0) {
        double usage = red[0];
        double mse = sum_sq[0] / (double)((size_t)N_TOK * E_DIM);
        out[LOSS_OFF] = (float)((1.0 + BETA) * mse + 0.01 * usage);
        out[PERP_OFF] = (float)exp(usage);
    }
}

extern "C" void kernel_launch(void* const* d_in, const int* in_sizes, int n_in,
                              void* d_out, int out_size, void* d_ws, size_t ws_size,
                              hipStream_t stream) {
    const float* z  = (const float*)d_in[0];
    const float* cb = (const float*)d_in[1];
    float* out = (float*)d_out;

    float*          c2     = (float*)((char*)d_ws + WS_C2);
    int*            counts = (int*)((char*)d_ws + WS_CNT);
    double*         sum_sq = (double*)((char*)d_ws + WS_SSQ);
    int*            wlc    = (int*)((char*)d_ws + WS_WLC);
    unsigned short* c2h    = (unsigned short*)((char*)d_ws + WS_C2H);
    unsigned short* fh     = (unsigned short*)((char*)d_ws + WS_FH);
    int*            wl     = (int*)((char*)d_ws + WS_WL);
    u64*            keys   = (u64*)((char*)d_ws + WS_KEYS);

    // u''-space margin (scaled x1024): 0.07 validated in round 1 (passed).
    float margin_u = (ws_size >= (size_t)(WS_KEYS + 8 * WLCAP)) ? 0.07f : 0.0f;

    frag_kernel<<<256, 256, 0, stream>>>(cb, fh, keys, c2, c2h, counts, wlc,
                                         sum_sq);
    vq_main<<<2048, 256, 0, stream>>>(z, cb, c2, c2h, fh, counts, sum_sq,
                                      wlc, wl, margin_u, out);
    fixup_scan<<<8192, 64, 0, stream>>>(z, cb, c2, wl, wlc, keys);
    fixup_apply<<<256, 256, 0, stream>>>(z, cb, wl, wlc, keys, counts,
                                         sum_sq, out);
    finalize_kernel<<<1, 1024, 0, stream>>>(counts, sum_sq, out);
}

// Round 3
// 310.008 us; speedup vs baseline: 1.0367x; 1.0367x over previous
//
#include <hip/hip_runtime.h>
#include <math.h>

#define N_TOK 131072
#define N_E   1024
#define E_DIM 64
#define BETA  0.4

// d_out layout (float32, concatenated in return order):
#define ZQ_OFF   0
#define LOSS_OFF 8388608
#define IDX_OFF  8388609
#define PERP_OFF 8519681

// d_ws layout (round-2 pass proved ws_size >= 532492; we use 338 KB):
#define WS_C2    0        // 1024 f32: RN32(exact ||c_e||^2)
#define WS_CNT   4096     // 1024 i32 counts
#define WS_SSQ   8192     // double sum_sq
#define WS_WLC   8200     // int worklist count (+4 pad)
#define WS_C2H   8208     // 2048 B: fp16(-512*c2)
#define WS_FH    10256    // 131072 B: fp16(codebook * 1024), MFMA B-frag layout
#define WS_WL    141328   // 16384 ints: worklist (flagged token ids)
#define WS_KEYS  206864   // 16384 u64: packed (d_bits<<32)|e per worklist slot
#define WLCAP    16384

typedef _Float16 f16x8 __attribute__((ext_vector_type(8)));
typedef float f32x4  __attribute__((ext_vector_type(4)));
typedef unsigned long long u64;

__device__ __forceinline__ void gl2lds16(const void* g, void* l) {
    __builtin_amdgcn_global_load_lds(
        (const __attribute__((address_space(1))) unsigned int*)g,
        (__attribute__((address_space(3))) unsigned int*)l, 16, 0, 0);
}

// top-2 second-place update in one VALU op: med3(k1,k2,key)
__device__ __forceinline__ unsigned med3u(unsigned a, unsigned b, unsigned c) {
    unsigned d;
    asm("v_med3_u32 %0, %1, %2, %3" : "=v"(d) : "v"(a), "v"(b), "v"(c));
    return d;
}

// Codebook -> fp16 MFMA B-fragment layout, scaled by 1024 (exact pow2) to keep
// all magnitudes >> fp16 denormal range. Also: exact-f32 c2 + fp16(-512*c2),
// counts/wlc/sum_sq zero-init, keys init.
__global__ void frag_kernel(const float* __restrict__ cb,
                            unsigned short* __restrict__ fh,
                            u64* __restrict__ keys,
                            float* __restrict__ c2,
                            unsigned short* __restrict__ c2h,
                            int* __restrict__ counts, int* __restrict__ wlc,
                            double* __restrict__ sum_sq) {
    int tid = blockIdx.x * 256 + threadIdx.x;   // 65536 total
    if (tid < WLCAP) keys[tid] = ~0ull;
    if (tid < N_E) {
        const float* p = cb + (size_t)tid * E_DIM;
        double s = 0.0;
#pragma unroll
        for (int k = 0; k < E_DIM; ++k) {
            double c = (double)p[k];
            s = fma(c, c, s);
        }
        float c2f = (float)s;
        c2[tid] = c2f;
        union { _Float16 h; unsigned short u; } q;
        q.h = (_Float16)(-512.0f * c2f);        // exact pow2 scale, then RN
        c2h[tid] = q.u;
        counts[tid] = 0;
        if (tid == 0) { *wlc = 0; *sum_sq = 0.0; }
    }
    int j  = tid & 7;
    int l  = (tid >> 3) & 63;
    int cc = tid >> 9;
    int code = (cc >> 1) * 16 + (l & 15);
    int k    = (cc & 1) * 32 + (l >> 4) * 8 + j;
    float f = cb[(size_t)code * E_DIM + k] * 1024.0f;  // exact pow2 scale
    union { _Float16 h; unsigned short s; } cv;
    cv.h = (_Float16)f;                                 // RN f32->f16
    fh[tid] = cv.s;
}

// Cold path (worklist overflow only). Exact numpy-f32 semantics, serial.
__device__ __attribute__((noinline)) int exact_best_serial(
    const float* __restrict__ z, const float* __restrict__ cb,
    const float* __restrict__ c2, int n) {
    const float* zr = z + (size_t)n * E_DIM;
    float r[8];
#pragma unroll
    for (int j = 0; j < 8; ++j) r[j] = __fmul_rn(zr[j], zr[j]);
#pragma unroll 1
    for (int i = 8; i < 64; i += 8)
#pragma unroll
        for (int j = 0; j < 8; ++j)
            r[j] = __fadd_rn(r[j], __fmul_rn(zr[i + j], zr[i + j]));
    float z2 = __fadd_rn(__fadd_rn(__fadd_rn(r[0], r[1]), __fadd_rn(r[2], r[3])),
                         __fadd_rn(__fadd_rn(r[4], r[5]), __fadd_rn(r[6], r[7])));
    u64 bestkey = ~0ull;
#pragma unroll 1
    for (int e = 0; e < N_E; ++e) {
        const float* cp = cb + (size_t)e * E_DIM;
        double m = 0.0;
#pragma unroll 1
        for (int i = 0; i < E_DIM; ++i)
            m = fma((double)zr[i], (double)cp[i], m);
        float d = __fsub_rn(__fadd_rn(z2, c2[e]), __fmul_rn(2.0f, (float)m));
        u64 key = ((u64)__float_as_uint(d) << 32) | (unsigned)e;
        if (key < bestkey) bestkey = key;
    }
    return (int)(bestkey & 0xffffffffu);
}

// Persistent screen: 256 blocks x 1024 threads (1 block/CU, 16 waves = 4/SIMD).
// Whole fp16 codebook (128 KB) staged to LDS ONCE; then each wave sweeps all
// 64 code-blocks for its 32 tokens with ZERO barriers / re-staging. Track max
// of u'' = 1024*dot - 512*c2 + 64 (> 0), key = (bits&~63)|(63-c).
__global__ __launch_bounds__(1024, 4) void vq_main(
    const float* __restrict__ z, const float* __restrict__ cb,
    const float* __restrict__ c2, const unsigned short* __restrict__ c2h_,
    const unsigned short* __restrict__ fh_,
    int* __restrict__ counts, double* __restrict__ sum_sq,
    int* __restrict__ wl_count, int* __restrict__ wl, float margin_u,
    float* __restrict__ out) {

    __shared__ __align__(16) unsigned char sbuf[131072];  // full fp16 codebook
    __shared__ __align__(8)  unsigned short c2s[N_E];     // fp16(-512*c2)
    __shared__ int   best_s[512];
    __shared__ unsigned char flag_s[512];
    __shared__ double wred[16];

    const int tid  = threadIdx.x;
    const int lane = tid & 63;
    const int wid  = tid >> 6;                 // 0..15
    const int col  = lane & 15;
    const int quad = lane >> 4;
    const int blk_tok0 = blockIdx.x * 512;
    const int wave_tok0 = blk_tok0 + wid * 32;

    // z loads first (their vmcnt completes independent of staging)
    float4 zl[2][4];
#pragma unroll
    for (int m = 0; m < 2; ++m) {
        const float* zr = z + (size_t)(wave_tok0 + m * 16 + col) * E_DIM + quad * 8;
#pragma unroll
        for (int kc = 0; kc < 2; ++kc) {
            zl[m][kc * 2]     = *(const float4*)(zr + kc * 32);
            zl[m][kc * 2 + 1] = *(const float4*)(zr + kc * 32 + 4);
        }
    }

    // stage whole codebook: 8 rounds x 16 KB (1024 thr x 16 B), linear
    const char* hsrc0 = (const char*)fh_;
#pragma unroll
    for (int r = 0; r < 8; ++r)
        gl2lds16(hsrc0 + r * 16384 + tid * 16, &sbuf[r * 16384 + wid * 1024]);
    if (tid < 128)
        gl2lds16((const char*)c2h_ + tid * 16,
                 (unsigned char*)c2s + (tid >> 6) * 1024);

    // convert A fragments while staging is in flight
    f16x8 Ah[2][2];
#pragma unroll
    for (int m = 0; m < 2; ++m)
#pragma unroll
        for (int kc = 0; kc < 2; ++kc) {
            float4 u0 = zl[m][kc * 2], u1 = zl[m][kc * 2 + 1];
            f16x8 a;
            a[0] = (_Float16)u0.x; a[1] = (_Float16)u0.y;
            a[2] = (_Float16)u0.z; a[3] = (_Float16)u0.w;
            a[4] = (_Float16)u1.x; a[5] = (_Float16)u1.y;
            a[6] = (_Float16)u1.z; a[7] = (_Float16)u1.w;
            Ah[m][kc] = a;
        }

    // packed-key top-2 MAX tracker
    unsigned k1[2][4], k2[2][4];
#pragma unroll
    for (int m = 0; m < 2; ++m)
#pragma unroll
        for (int r = 0; r < 4; ++r) { k1[m][r] = 0u; k2[m][r] = 0u; }

    __syncthreads();   // staging complete; ONLY barrier before the sweep

#pragma unroll 4
    for (int cl = 0; cl < 64; ++cl) {
        const unsigned char* bp = sbuf + cl * 2048 + lane * 16;
        union { uint4 u; f16x8 v; } b0, b1;
        b0.u = *(const uint4*)(bp);
        b1.u = *(const uint4*)(bp + 1024);
        union { unsigned short us; _Float16 h; } cv;
        cv.us = c2s[cl * 16 + col];
        const float ch = 64.0f + (float)cv.h;
        const f32x4 cinit = {ch, ch, ch, ch};
        const unsigned ctag = (unsigned)(63 - cl);
#pragma unroll
        for (int m = 0; m < 2; ++m) {
            f32x4 acc = __builtin_amdgcn_mfma_f32_16x16x32_f16(
                Ah[m][0], b0.v, cinit, 0, 0, 0);
            acc = __builtin_amdgcn_mfma_f32_16x16x32_f16(
                Ah[m][1], b1.v, acc, 0, 0, 0);
#pragma unroll
            for (int r = 0; r < 4; ++r) {
                unsigned key = (__float_as_uint(acc[r]) & 0xFFFFFFC0u) | ctag;
                k2[m][r] = med3u(k1[m][r], k2[m][r], key);
                k1[m][r] = max(k1[m][r], key);
            }
        }
    }

    // merge + decide, per (m,r): maximize u'', tie -> lowest code index
#pragma unroll
    for (int m = 0; m < 2; ++m) {
#pragma unroll
        for (int r = 0; r < 4; ++r) {
            float v1 = __uint_as_float(k1[m][r] & 0xFFFFFFC0u);
            float v2 = __uint_as_float(k2[m][r] & 0xFFFFFFC0u);
            int   b1 = (63 - (int)(k1[m][r] & 63u)) * 16 + col;
#pragma unroll
            for (int d = 1; d < 16; d <<= 1) {
                float o1 = __shfl_xor(v1, d, 64);
                float o2 = __shfl_xor(v2, d, 64);
                int   ob = __shfl_xor(b1, d, 64);
                float n2 = fmaxf(fmaxf(v2, o2), fminf(v1, o1));
                bool take = (o1 > v1) || (o1 == v1 && ob < b1);
                v1 = fmaxf(v1, o1);
                b1 = take ? ob : b1;
                v2 = n2;
            }
            if (col == 0) {
                int tl = wid * 32 + m * 16 + quad * 4 + r;
                int n  = blk_tok0 + tl;
                int best = b1;
                bool fl = (v1 - v2) < margin_u;
                if (fl) {
                    int pos = atomicAdd(wl_count, 1);
                    if (pos < WLCAP) wl[pos] = n;
                    else { best = exact_best_serial(z, cb, c2, n); fl = false; }
                }
                best_s[tl] = best;
                flag_s[tl] = fl ? 1 : 0;
                if (!fl) atomicAdd(&counts[best], 1);
            }
        }
    }

    // per-wave coalesced idx write (same-wave LDS visibility; no barrier)
    if (lane < 32)
        out[IDX_OFF + wave_tok0 + lane] = (float)best_s[wid * 32 + lane];

    // per-wave epilogue: coalesced z_q / loss for unflagged tokens
    const int sub = lane & 15, grp = lane >> 4;
    double dl = 0.0;
    const float4* zrow = (const float4*)z;
    const float4* crow = (const float4*)cb;
    float4* qrow = (float4*)(out + ZQ_OFF);
#pragma unroll
    for (int p = 0; p < 8; ++p) {
        int tl = wid * 32 + p * 4 + grp;
        if (!flag_s[tl]) {
            int n = blk_tok0 + tl;
            float4 z4 = zrow[(size_t)n * 16 + sub];
            float4 c4 = crow[(size_t)best_s[tl] * 16 + sub];
            float dx = c4.x - z4.x, dy = c4.y - z4.y;
            float dz = c4.z - z4.z, dw = c4.w - z4.w;
            float4 q;
            q.x = z4.x + dx; q.y = z4.y + dy;
            q.z = z4.z + dz; q.w = z4.w + dw;
            qrow[(size_t)n * 16 + sub] = q;
            dl += (double)dx * dx + (double)dy * dy
                + (double)dz * dz + (double)dw * dw;
        }
    }
#pragma unroll
    for (int off = 32; off > 0; off >>= 1)
        dl += __shfl_down(dl, off, 64);
    if (lane == 0) wred[wid] = dl;
    __syncthreads();
    if (tid == 0) {
        double s = 0.0;
#pragma unroll
        for (int i = 0; i < 16; ++i) s += wred[i];
        atomicAdd(sum_sq, s);
    }
}

// Scan: one wave per (64-token group x 32-code slice); token-per-lane,
// wave-uniform cb rows. f32 prescreen gates exact-f64 refine to ~1 code/lane.
// delta = 4e-3 >> 2x f32-comparison error (<1e-4); z2 offset cancels in the
// d32 comparisons. Exact path arithmetic identical to validated version.
__global__ __launch_bounds__(64) void fixup_scan(
    const float* __restrict__ z, const float* __restrict__ cb,
    const float* __restrict__ c2, const int* __restrict__ wl,
    const int* __restrict__ wl_count, u64* __restrict__ keys) {

    int count = *wl_count; if (count > WLCAP) count = WLCAP;
    const int g = blockIdx.x >> 5;        // token group (64 per group)
    const int s = blockIdx.x & 31;        // code slice (32 codes)
    if (g * 64 >= count) return;
    const int lane = threadIdx.x;
    const int w = g * 64 + lane;
    const bool valid = w < count;
    const int n = wl[valid ? w : g * 64];

    float zf[E_DIM];
    const float4* zp = (const float4*)(z + (size_t)n * E_DIM);
#pragma unroll
    for (int k = 0; k < 16; ++k) {
        float4 v = zp[k];
        zf[4 * k]     = v.x;
        zf[4 * k + 1] = v.y;
        zf[4 * k + 2] = v.z;
        zf[4 * k + 3] = v.w;
    }
    // numpy-pairwise z2 in f32 (8 accumulators + tree)
    float r8[8];
#pragma unroll
    for (int j = 0; j < 8; ++j) r8[j] = __fmul_rn(zf[j], zf[j]);
#pragma unroll
    for (int i = 8; i < 64; i += 8)
#pragma unroll
        for (int j = 0; j < 8; ++j)
            r8[j] = __fadd_rn(r8[j], __fmul_rn(zf[i + j], zf[i + j]));
    const float z2 = __fadd_rn(
        __fadd_rn(__fadd_rn(r8[0], r8[1]), __fadd_rn(r8[2], r8[3])),
        __fadd_rn(__fadd_rn(r8[4], r8[5]), __fadd_rn(r8[6], r8[7])));

    const int e0 = s * 32;

    // f32 prescreen of all 32 codes (wave-uniform cb rows -> scalar loads)
    float d32[32];
    float dmin = 1e30f;
#pragma unroll 4
    for (int i = 0; i < 32; ++i) {
        const float* cp = cb + (size_t)(e0 + i) * E_DIM;
        float a0 = 0.f, a1 = 0.f, a2 = 0.f, a3 = 0.f;
#pragma unroll
        for (int k = 0; k < 64; k += 4) {
            a0 = fmaf(zf[k],     cp[k],     a0);
            a1 = fmaf(zf[k + 1], cp[k + 1], a1);
            a2 = fmaf(zf[k + 2], cp[k + 2], a2);
            a3 = fmaf(zf[k + 3], cp[k + 3], a3);
        }
        float d = z2 + c2[e0 + i] - 2.0f * ((a0 + a1) + (a2 + a3));
        d32[i] = d;
        dmin = fminf(dmin, d);
    }

    // exact-f64 refine of every code within delta of the slice min
    u64 best = ~0ull;
    const float thr = dmin + 4e-3f;
    for (int it = 0; it < 32; ++it) {
        float dm = d32[0]; int am = 0;
#pragma unroll
        for (int i = 1; i < 32; ++i) {
            bool t = d32[i] < dm;
            dm = t ? d32[i] : dm;
            am = t ? i : am;
        }
        bool need = dm <= thr;
        if (!__any(need)) break;
        if (need) {
            int e = e0 + am;
            const float* cp = cb + (size_t)e * E_DIM;
            double m = 0.0;
#pragma unroll
            for (int i = 0; i < E_DIM; ++i)
                m = fma((double)zf[i], (double)cp[i], m);
            float d = __fsub_rn(__fadd_rn(z2, c2[e]), __fmul_rn(2.0f, (float)m));
            u64 key = ((u64)__float_as_uint(d) << 32) | (unsigned)e;
            if (key < best) best = key;
#pragma unroll
            for (int i = 0; i < 32; ++i)     // static-indexed invalidate
                if (i == am) d32[i] = 1e30f;
        }
    }
    if (valid && best != ~0ull) atomicMin(&keys[w], best);
}

// Apply: one wave per worklist token; finish zq/idx/counts/sum_sq.
__global__ __launch_bounds__(256) void fixup_apply(
    const float* __restrict__ z, const float* __restrict__ cb,
    const int* __restrict__ wl, const int* __restrict__ wl_count,
    const u64* __restrict__ keys, int* __restrict__ counts,
    double* __restrict__ sum_sq, float* __restrict__ out) {

    int count = *wl_count; if (count > WLCAP) count = WLCAP;
    const int lane = threadIdx.x & 63;
    const int gw = blockIdx.x * 4 + (threadIdx.x >> 6);
    for (int w = gw; w < count; w += 1024) {
        const int n = wl[w];
        const int best = (int)(keys[w] & 0xffffffffull);
        float cv = cb[(size_t)best * E_DIM + lane];
        float zi = z[(size_t)n * E_DIM + lane];
        float diff = cv - zi;
        out[ZQ_OFF + (size_t)n * E_DIM + lane] = zi + diff;
        double d2 = (double)diff * (double)diff;
#pragma unroll
        for (int off = 32; off > 0; off >>= 1)
            d2 += __shfl_down(d2, off, 64);
        if (lane == 0) {
            atomicAdd(sum_sq, d2);
            atomicAdd(&counts[best], 1);
            out[IDX_OFF + n] = (float)best;
        }
    }
}

__global__ __launch_bounds__(1024) void finalize_kernel(
    const int* __restrict__ counts, const double* __restrict__ sum_sq,
    float* __restrict__ out) {
    __shared__ double red[1024];
    int e = threadIdx.x;
    double em = (double)counts[e] / (double)N_TOK;
    red[e] = -em * log(em + 1e-10);
    __syncthreads();
    for (int s = 512; s > 0; s >>= 1) {
        if (e < s) red[e] += red[e + s];
        __syncthreads();
    }
    if (e == 0) {
        double usage = red[0];
        double mse = sum_sq[0] / (double)((size_t)N_TOK * E_DIM);
        out[LOSS_OFF] = (float)((1.0 + BETA) * mse + 0.01 * usage);
        out[PERP_OFF] = (float)exp(usage);
    }
}

extern "C" void kernel_launch(void* const* d_in, const int* in_sizes, int n_in,
                              void* d_out, int out_size, void* d_ws, size_t ws_size,
                              hipStream_t stream) {
    const float* z  = (const float*)d_in[0];
    const float* cb = (const float*)d_in[1];
    float* out = (float*)d_out;

    float*          c2     = (float*)((char*)d_ws + WS_C2);
    int*            counts = (int*)((char*)d_ws + WS_CNT);
    double*         sum_sq = (double*)((char*)d_ws + WS_SSQ);
    int*            wlc    = (int*)((char*)d_ws + WS_WLC);
    unsigned short* c2h    = (unsigned short*)((char*)d_ws + WS_C2H);
    unsigned short* fh     = (unsigned short*)((char*)d_ws + WS_FH);
    int*            wl     = (int*)((char*)d_ws + WS_WL);
    u64*            keys   = (u64*)((char*)d_ws + WS_KEYS);

    // u''-space margin (scaled x1024): 0.07 validated in rounds 1-2 (passed).
    float margin_u = (ws_size >= (size_t)(WS_KEYS + 8 * WLCAP)) ? 0.07f : 0.0f;

    frag_kernel<<<256, 256, 0, stream>>>(cb, fh, keys, c2, c2h, counts, wlc,
                                         sum_sq);
    vq_main<<<256, 1024, 0, stream>>>(z, cb, c2, c2h, fh, counts, sum_sq,
                                      wlc, wl, margin_u, out);
    fixup_scan<<<8192, 64, 0, stream>>>(z, cb, c2, wl, wlc, keys);
    fixup_apply<<<256, 256, 0, stream>>>(z, cb, wl, wlc, keys, counts,
                                         sum_sq, out);
    finalize_kernel<<<1, 1024, 0, stream>>>(counts, sum_sq, out);
}

// Round 4
// 225.060 us; speedup vs baseline: 1.4280x; 1.3774x over previous
//
#include <hip/hip_runtime.h>
#include <math.h>

#define N_TOK 131072
#define N_E   1024
#define E_DIM 64
#define BETA  0.4

// d_out layout (float32, concatenated in return order):
#define ZQ_OFF   0
#define LOSS_OFF 8388608
#define IDX_OFF  8388609
#define PERP_OFF 8519681

// d_ws layout (round-2 pass proved ws_size >= 532492; we use 371 KB):
#define WS_C2    0        // 1024 f32: RN32(exact ||c_e||^2)
#define WS_CNT   4096     // 1024 i32 counts
#define WS_SSQ   8192     // double sum_sq
#define WS_WLC   8200     // int x2: worklist counts (A=2cand, B=full)
#define WS_C2H   8208     // 2048 B: fp16(-512*c2)
#define WS_FH    10256    // 131072 B: fp16(codebook * 1024), MFMA B-frag layout
#define WS_WLA   141328   // 16384 u64: (n<<32)|(b1<<16)|b2  2-candidate list
#define WS_WLB   272400   // 8192 ints: full-scan token ids
#define WS_KEYSB 305168   // 8192 u64: packed (d_bits<<32)|e per B slot
#define WLCAP_A  16384
#define WLCAP_B  8192

typedef _Float16 f16x8 __attribute__((ext_vector_type(8)));
typedef float f32x4  __attribute__((ext_vector_type(4)));
typedef unsigned long long u64;

__device__ __forceinline__ void gl2lds16(const void* g, void* l) {
    __builtin_amdgcn_global_load_lds(
        (const __attribute__((address_space(1))) unsigned int*)g,
        (__attribute__((address_space(3))) unsigned int*)l, 16, 0, 0);
}

__device__ __forceinline__ unsigned med3u(unsigned a, unsigned b, unsigned c) {
    unsigned d;
    asm("v_med3_u32 %0, %1, %2, %3" : "=v"(d) : "v"(a), "v"(b), "v"(c));
    return d;
}

// Codebook -> fp16 MFMA B-fragment layout (scaled x1024, exact pow2).
// Also: exact-f32 c2 + fp16(-512*c2), counters zero-init, keysB init.
__global__ void frag_kernel(const float* __restrict__ cb,
                            unsigned short* __restrict__ fh,
                            u64* __restrict__ keysB,
                            float* __restrict__ c2,
                            unsigned short* __restrict__ c2h,
                            int* __restrict__ counts, int* __restrict__ wlc,
                            double* __restrict__ sum_sq) {
    int tid = blockIdx.x * 256 + threadIdx.x;   // 65536 total
    if (tid < WLCAP_B) keysB[tid] = ~0ull;
    if (tid < N_E) {
        const float* p = cb + (size_t)tid * E_DIM;
        double s = 0.0;
#pragma unroll
        for (int k = 0; k < E_DIM; ++k) {
            double c = (double)p[k];
            s = fma(c, c, s);
        }
        float c2f = (float)s;
        c2[tid] = c2f;
        union { _Float16 h; unsigned short u; } q;
        q.h = (_Float16)(-512.0f * c2f);
        c2h[tid] = q.u;
        counts[tid] = 0;
        if (tid == 0) { wlc[0] = 0; wlc[1] = 0; *sum_sq = 0.0; }
    }
    int j  = tid & 7;
    int l  = (tid >> 3) & 63;
    int cc = tid >> 9;
    int code = (cc >> 1) * 16 + (l & 15);
    int k    = (cc & 1) * 32 + (l >> 4) * 8 + j;
    float f = cb[(size_t)code * E_DIM + k] * 1024.0f;
    union { _Float16 h; unsigned short s; } cv;
    cv.h = (_Float16)f;
    fh[tid] = cv.s;
}

// Cold path (worklist overflow only). Exact numpy-f32 semantics, serial.
__device__ __attribute__((noinline)) int exact_best_serial(
    const float* __restrict__ z, const float* __restrict__ cb,
    const float* __restrict__ c2, int n) {
    const float* zr = z + (size_t)n * E_DIM;
    float r[8];
#pragma unroll
    for (int j = 0; j < 8; ++j) r[j] = __fmul_rn(zr[j], zr[j]);
#pragma unroll 1
    for (int i = 8; i < 64; i += 8)
#pragma unroll
        for (int j = 0; j < 8; ++j)
            r[j] = __fadd_rn(r[j], __fmul_rn(zr[i + j], zr[i + j]));
    float z2 = __fadd_rn(__fadd_rn(__fadd_rn(r[0], r[1]), __fadd_rn(r[2], r[3])),
                         __fadd_rn(__fadd_rn(r[4], r[5]), __fadd_rn(r[6], r[7])));
    u64 bestkey = ~0ull;
#pragma unroll 1
    for (int e = 0; e < N_E; ++e) {
        const float* cp = cb + (size_t)e * E_DIM;
        double m = 0.0;
#pragma unroll 1
        for (int i = 0; i < E_DIM; ++i)
            m = fma((double)zr[i], (double)cp[i], m);
        float d = __fsub_rn(__fadd_rn(z2, c2[e]), __fmul_rn(2.0f, (float)m));
        u64 key = ((u64)__float_as_uint(d) << 32) | (unsigned)e;
        if (key < bestkey) bestkey = key;
    }
    return (int)(bestkey & 0xffffffffu);
}

// Persistent screen: 256 blocks x 1024 threads. Whole fp16 codebook in LDS
// once; zero-barrier sweep. Top-3 packed-key tracker: key =
// (u''_bits & ~63) | (63-cl); u'' = 1024*dot - 512*c2 + 64 > 0.
// Routing: v1-v2>=m -> settled; v1-v3>=m -> 2-candidate exact (wlA);
// else / ambiguous recovery -> full scan (wlB). Per-wave ballot-aggregated
// worklist atomics.
__global__ __launch_bounds__(1024, 4) void vq_main(
    const float* __restrict__ z, const float* __restrict__ cb,
    const float* __restrict__ c2, const unsigned short* __restrict__ c2h_,
    const unsigned short* __restrict__ fh_,
    int* __restrict__ counts, double* __restrict__ sum_sq,
    int* __restrict__ wlc, u64* __restrict__ wlA, int* __restrict__ wlB,
    float margin_u, float* __restrict__ out) {

    __shared__ __align__(16) unsigned char sbuf[131072];
    __shared__ __align__(8)  unsigned short c2s[N_E];
    __shared__ int   best_s[512];
    __shared__ unsigned char flag_s[512];
    __shared__ double wred[16];

    const int tid  = threadIdx.x;
    const int lane = tid & 63;
    const int wid  = tid >> 6;
    const int col  = lane & 15;
    const int quad = lane >> 4;
    const int blk_tok0 = blockIdx.x * 512;
    const int wave_tok0 = blk_tok0 + wid * 32;

    float4 zl[2][4];
#pragma unroll
    for (int m = 0; m < 2; ++m) {
        const float* zr = z + (size_t)(wave_tok0 + m * 16 + col) * E_DIM + quad * 8;
#pragma unroll
        for (int kc = 0; kc < 2; ++kc) {
            zl[m][kc * 2]     = *(const float4*)(zr + kc * 32);
            zl[m][kc * 2 + 1] = *(const float4*)(zr + kc * 32 + 4);
        }
    }

    const char* hsrc0 = (const char*)fh_;
#pragma unroll
    for (int r = 0; r < 8; ++r)
        gl2lds16(hsrc0 + r * 16384 + tid * 16, &sbuf[r * 16384 + wid * 1024]);
    if (tid < 128)
        gl2lds16((const char*)c2h_ + tid * 16,
                 (unsigned char*)c2s + (tid >> 6) * 1024);

    f16x8 Ah[2][2];
#pragma unroll
    for (int m = 0; m < 2; ++m)
#pragma unroll
        for (int kc = 0; kc < 2; ++kc) {
            float4 u0 = zl[m][kc * 2], u1 = zl[m][kc * 2 + 1];
            f16x8 a;
            a[0] = (_Float16)u0.x; a[1] = (_Float16)u0.y;
            a[2] = (_Float16)u0.z; a[3] = (_Float16)u0.w;
            a[4] = (_Float16)u1.x; a[5] = (_Float16)u1.y;
            a[6] = (_Float16)u1.z; a[7] = (_Float16)u1.w;
            Ah[m][kc] = a;
        }

    unsigned k1[2][4], k2[2][4], k3[2][4];
#pragma unroll
    for (int m = 0; m < 2; ++m)
#pragma unroll
        for (int r = 0; r < 4; ++r) { k1[m][r] = 0u; k2[m][r] = 0u; k3[m][r] = 0u; }

    __syncthreads();   // staging complete; only barrier before sweep

#pragma unroll 4
    for (int cl = 0; cl < 64; ++cl) {
        const unsigned char* bp = sbuf + cl * 2048 + lane * 16;
        union { uint4 u; f16x8 v; } b0, b1;
        b0.u = *(const uint4*)(bp);
        b1.u = *(const uint4*)(bp + 1024);
        union { unsigned short us; _Float16 h; } cv;
        cv.us = c2s[cl * 16 + col];
        const float ch = 64.0f + (float)cv.h;
        const f32x4 cinit = {ch, ch, ch, ch};
        const unsigned ctag = (unsigned)(63 - cl);
#pragma unroll
        for (int m = 0; m < 2; ++m) {
            f32x4 acc = __builtin_amdgcn_mfma_f32_16x16x32_f16(
                Ah[m][0], b0.v, cinit, 0, 0, 0);
            acc = __builtin_amdgcn_mfma_f32_16x16x32_f16(
                Ah[m][1], b1.v, acc, 0, 0, 0);
#pragma unroll
            for (int r = 0; r < 4; ++r) {
                unsigned key = (__float_as_uint(acc[r]) & 0xFFFFFFC0u) | ctag;
                unsigned t1 = min(k1[m][r], key);
                k3[m][r] = med3u(k2[m][r], k3[m][r], t1);   // old k2
                k2[m][r] = med3u(k1[m][r], k2[m][r], key);  // old k1
                k1[m][r] = max(k1[m][r], key);
            }
        }
    }

    // merge + route, per (m,r)
#pragma unroll 1
    for (int m = 0; m < 2; ++m) {
#pragma unroll 1
        for (int r = 0; r < 4; ++r) {
            const unsigned l1 = k1[m][r], l2 = k2[m][r], l3 = k3[m][r];
            unsigned g1 = l1, g2 = l2, g3 = l3;
#pragma unroll
            for (int d = 1; d < 16; d <<= 1) {
                unsigned p1 = __shfl_xor(g1, d, 64);
                unsigned p2 = __shfl_xor(g2, d, 64);
                unsigned p3 = __shfl_xor(g3, d, 64);
                unsigned t1 = min(g1, p1);
                g3 = med3u(g2, g3, t1);
                g2 = med3u(g1, g2, p1);
                g1 = max(g1, p1);
                g3 = med3u(g2, g3, p2);     // p2 <= p1: slots 2,3 only
                g2 = max(g2, p2);
                g3 = med3u(g2, g3, p3);     // p3 <= p2: slot 3 only
            }
            // ballot recovery of candidate cols (all lanes participate)
            u64 bal1 = __ballot((l1 == g1) || (l2 == g1) || (l3 == g1));
            u64 bal2 = __ballot((l1 == g2) || (l2 == g2) || (l3 == g2));

            const int tl = wid * 32 + m * 16 + quad * 4 + r;
            const int n  = blk_tok0 + tl;
            int typ = 0;        // 0 settled, 1 = 2-cand, 2 = full scan
            int bbest = 0, bsec = 0;
            if (col == 0) {
                unsigned m1 = (unsigned)((bal1 >> (quad * 16)) & 0xFFFFu);
                int c1 = __ffs(m1) - 1;
                bbest = (63 - (int)(g1 & 63u)) * 16 + c1;
                float v1 = __uint_as_float(g1 & 0xFFFFFFC0u);
                float v2 = __uint_as_float(g2 & 0xFFFFFFC0u);
                float v3 = __uint_as_float(g3 & 0xFFFFFFC0u);
                if (v1 - v2 < margin_u) {
                    if (v1 - v3 < margin_u) typ = 2;
                    else {
                        unsigned m2 = (unsigned)((bal2 >> (quad * 16)) & 0xFFFFu);
                        if (g2 == g1) m2 &= ~(1u << c1);
                        int pc = __popc(m2);
                        if (pc == 1) {
                            bsec = (63 - (int)(g2 & 63u)) * 16 + (__ffs(m2) - 1);
                            typ = 1;
                        } else typ = 2;   // ambiguous recovery -> full
                    }
                }
            }
            // per-wave aggregated worklist appends
            u64 balA = __ballot(typ == 1);
            if (balA) {
                int lead = __ffsll((unsigned long long)balA) - 1;
                int cnt  = __popcll(balA);
                int base = 0;
                if (lane == lead) base = atomicAdd(&wlc[0], cnt);
                base = __shfl(base, lead, 64);
                if (typ == 1) {
                    int pos = base + __popcll(balA & ((1ull << lane) - 1ull));
                    if (pos < WLCAP_A)
                        wlA[pos] = ((u64)(unsigned)n << 32) |
                                   ((unsigned)(bbest << 16) | (unsigned)bsec);
                    else { bbest = exact_best_serial(z, cb, c2, n); typ = 0; }
                }
            }
            u64 balB = __ballot(typ == 2);
            if (balB) {
                int lead = __ffsll((unsigned long long)balB) - 1;
                int cnt  = __popcll(balB);
                int base = 0;
                if (lane == lead) base = atomicAdd(&wlc[1], cnt);
                base = __shfl(base, lead, 64);
                if (typ == 2) {
                    int pos = base + __popcll(balB & ((1ull << lane) - 1ull));
                    if (pos < WLCAP_B) wlB[pos] = n;
                    else { bbest = exact_best_serial(z, cb, c2, n); typ = 0; }
                }
            }
            if (col == 0) {
                best_s[tl] = bbest;
                flag_s[tl] = (typ != 0) ? 1 : 0;
                if (typ == 0) atomicAdd(&counts[bbest], 1);
            }
        }
    }

    // per-wave coalesced idx write (deferred slots overwritten later)
    if (lane < 32)
        out[IDX_OFF + wave_tok0 + lane] = (float)best_s[wid * 32 + lane];

    // per-wave epilogue: coalesced z_q / loss for settled tokens
    const int sub = lane & 15, grp = lane >> 4;
    double dl = 0.0;
    const float4* zrow = (const float4*)z;
    const float4* crow = (const float4*)cb;
    float4* qrow = (float4*)(out + ZQ_OFF);
#pragma unroll
    for (int p = 0; p < 8; ++p) {
        int tl = wid * 32 + p * 4 + grp;
        if (!flag_s[tl]) {
            int n = blk_tok0 + tl;
            float4 z4 = zrow[(size_t)n * 16 + sub];
            float4 c4 = crow[(size_t)best_s[tl] * 16 + sub];
            float dx = c4.x - z4.x, dy = c4.y - z4.y;
            float dz = c4.z - z4.z, dw = c4.w - z4.w;
            float4 q;
            q.x = z4.x + dx; q.y = z4.y + dy;
            q.z = z4.z + dz; q.w = z4.w + dw;
            qrow[(size_t)n * 16 + sub] = q;
            dl += (double)dx * dx + (double)dy * dy
                + (double)dz * dz + (double)dw * dw;
        }
    }
#pragma unroll
    for (int off = 32; off > 0; off >>= 1)
        dl += __shfl_down(dl, off, 64);
    if (lane == 0) wred[wid] = dl;
    __syncthreads();
    if (tid == 0) {
        double s = 0.0;
#pragma unroll
        for (int i = 0; i < 16; ++i) s += wred[i];
        atomicAdd(sum_sq, s);
    }
}

// 2-candidate exact fixup: one thread per wlA entry. Exact-f64 dots for the
// two recovered candidates; finish zq/idx/counts/sum_sq for those tokens.
__global__ __launch_bounds__(256) void cand_fix(
    const float* __restrict__ z, const float* __restrict__ cb,
    const float* __restrict__ c2, const u64* __restrict__ wlA,
    const int* __restrict__ wlc, int* __restrict__ counts,
    double* __restrict__ sum_sq, float* __restrict__ out) {

    int count = wlc[0]; if (count > WLCAP_A) count = WLCAP_A;
    double d2acc = 0.0;
    for (int w = blockIdx.x * 256 + threadIdx.x; w < count;
         w += gridDim.x * 256) {
        u64 ent = wlA[w];
        int n  = (int)(ent >> 32);
        int e1 = (int)((ent >> 16) & 0xFFFFu);
        int e2 = (int)(ent & 0xFFFFu);
        float zf[E_DIM];
        const float4* zp = (const float4*)(z + (size_t)n * E_DIM);
#pragma unroll
        for (int k = 0; k < 16; ++k) {
            float4 v = zp[k];
            zf[4 * k] = v.x; zf[4 * k + 1] = v.y;
            zf[4 * k + 2] = v.z; zf[4 * k + 3] = v.w;
        }
        float r8[8];
#pragma unroll
        for (int j = 0; j < 8; ++j) r8[j] = __fmul_rn(zf[j], zf[j]);
#pragma unroll
        for (int i = 8; i < 64; i += 8)
#pragma unroll
            for (int j = 0; j < 8; ++j)
                r8[j] = __fadd_rn(r8[j], __fmul_rn(zf[i + j], zf[i + j]));
        float z2 = __fadd_rn(
            __fadd_rn(__fadd_rn(r8[0], r8[1]), __fadd_rn(r8[2], r8[3])),
            __fadd_rn(__fadd_rn(r8[4], r8[5]), __fadd_rn(r8[6], r8[7])));
        u64 bk = ~0ull;
#pragma unroll
        for (int t = 0; t < 2; ++t) {
            int e = t ? e2 : e1;
            const float* cp = cb + (size_t)e * E_DIM;
            double mm = 0.0;
#pragma unroll
            for (int i = 0; i < E_DIM; ++i)
                mm = fma((double)zf[i], (double)cp[i], mm);
            float d = __fsub_rn(__fadd_rn(z2, c2[e]),
                                __fmul_rn(2.0f, (float)mm));
            u64 key = ((u64)__float_as_uint(d) << 32) | (unsigned)e;
            if (key < bk) bk = key;
        }
        int best = (int)(bk & 0xffffffffu);
        const float4* cp4 = (const float4*)(cb + (size_t)best * E_DIM);
        float4* qp = (float4*)(out + ZQ_OFF + (size_t)n * E_DIM);
        double d2 = 0.0;
#pragma unroll
        for (int k = 0; k < 16; ++k) {
            float4 c4 = cp4[k];
            float dx = c4.x - zf[4 * k],     dy = c4.y - zf[4 * k + 1];
            float dzv = c4.z - zf[4 * k + 2], dw = c4.w - zf[4 * k + 3];
            float4 q;
            q.x = zf[4 * k] + dx;     q.y = zf[4 * k + 1] + dy;
            q.z = zf[4 * k + 2] + dzv; q.w = zf[4 * k + 3] + dw;
            qp[k] = q;
            d2 += (double)dx * dx + (double)dy * dy
                + (double)dzv * dzv + (double)dw * dw;
        }
        out[IDX_OFF + n] = (float)best;
        atomicAdd(&counts[best], 1);
        d2acc += d2;
    }
#pragma unroll
    for (int off = 32; off > 0; off >>= 1)
        d2acc += __shfl_down(d2acc, off, 64);
    if ((threadIdx.x & 63) == 0 && d2acc != 0.0) atomicAdd(sum_sq, d2acc);
}

// Full scan for wlB tokens: one wave per (64-token group x 32-code slice).
// f32 prescreen gates exact-f64 refine (validated round 3).
__global__ __launch_bounds__(64) void fixup_scan(
    const float* __restrict__ z, const float* __restrict__ cb,
    const float* __restrict__ c2, const int* __restrict__ wlB,
    const int* __restrict__ wlc, u64* __restrict__ keysB) {

    int count = wlc[1]; if (count > WLCAP_B) count = WLCAP_B;
    const int g = blockIdx.x >> 5;
    const int s = blockIdx.x & 31;
    if (g * 64 >= count) return;
    const int lane = threadIdx.x;
    const int w = g * 64 + lane;
    const bool valid = w < count;
    const int n = wlB[valid ? w : g * 64];

    float zf[E_DIM];
    const float4* zp = (const float4*)(z + (size_t)n * E_DIM);
#pragma unroll
    for (int k = 0; k < 16; ++k) {
        float4 v = zp[k];
        zf[4 * k] = v.x; zf[4 * k + 1] = v.y;
        zf[4 * k + 2] = v.z; zf[4 * k + 3] = v.w;
    }
    float r8[8];
#pragma unroll
    for (int j = 0; j < 8; ++j) r8[j] = __fmul_rn(zf[j], zf[j]);
#pragma unroll
    for (int i = 8; i < 64; i += 8)
#pragma unroll
        for (int j = 0; j < 8; ++j)
            r8[j] = __fadd_rn(r8[j], __fmul_rn(zf[i + j], zf[i + j]));
    const float z2 = __fadd_rn(
        __fadd_rn(__fadd_rn(r8[0], r8[1]), __fadd_rn(r8[2], r8[3])),
        __fadd_rn(__fadd_rn(r8[4], r8[5]), __fadd_rn(r8[6], r8[7])));

    const int e0 = s * 32;
    float d32[32];
    float dmin = 1e30f;
#pragma unroll 4
    for (int i = 0; i < 32; ++i) {
        const float* cp = cb + (size_t)(e0 + i) * E_DIM;
        float a0 = 0.f, a1 = 0.f, a2 = 0.f, a3 = 0.f;
#pragma unroll
        for (int k = 0; k < 64; k += 4) {
            a0 = fmaf(zf[k],     cp[k],     a0);
            a1 = fmaf(zf[k + 1], cp[k + 1], a1);
            a2 = fmaf(zf[k + 2], cp[k + 2], a2);
            a3 = fmaf(zf[k + 3], cp[k + 3], a3);
        }
        float d = z2 + c2[e0 + i] - 2.0f * ((a0 + a1) + (a2 + a3));
        d32[i] = d;
        dmin = fminf(dmin, d);
    }
    u64 best = ~0ull;
    const float thr = dmin + 4e-3f;
    for (int it = 0; it < 32; ++it) {
        float dm = d32[0]; int am = 0;
#pragma unroll
        for (int i = 1; i < 32; ++i) {
            bool t = d32[i] < dm;
            dm = t ? d32[i] : dm;
            am = t ? i : am;
        }
        bool need = dm <= thr;
        if (!__any(need)) break;
        if (need) {
            int e = e0 + am;
            const float* cp = cb + (size_t)e * E_DIM;
            double mm = 0.0;
#pragma unroll
            for (int i = 0; i < E_DIM; ++i)
                mm = fma((double)zf[i], (double)cp[i], mm);
            float d = __fsub_rn(__fadd_rn(z2, c2[e]),
                                __fmul_rn(2.0f, (float)mm));
            u64 key = ((u64)__float_as_uint(d) << 32) | (unsigned)e;
            if (key < best) best = key;
#pragma unroll
            for (int i = 0; i < 32; ++i)
                if (i == am) d32[i] = 1e30f;
        }
    }
    if (valid && best != ~0ull) atomicMin(&keysB[w], best);
}

// Apply full-scan results.
__global__ __launch_bounds__(256) void fixup_apply(
    const float* __restrict__ z, const float* __restrict__ cb,
    const int* __restrict__ wlB, const int* __restrict__ wlc,
    const u64* __restrict__ keysB, int* __restrict__ counts,
    double* __restrict__ sum_sq, float* __restrict__ out) {

    int count = wlc[1]; if (count > WLCAP_B) count = WLCAP_B;
    const int lane = threadIdx.x & 63;
    const int gw = blockIdx.x * 4 + (threadIdx.x >> 6);
    for (int w = gw; w < count; w += 1024) {
        const int n = wlB[w];
        const int best = (int)(keysB[w] & 0xffffffffull);
        float cv = cb[(size_t)best * E_DIM + lane];
        float zi = z[(size_t)n * E_DIM + lane];
        float diff = cv - zi;
        out[ZQ_OFF + (size_t)n * E_DIM + lane] = zi + diff;
        double d2 = (double)diff * (double)diff;
#pragma unroll
        for (int off = 32; off > 0; off >>= 1)
            d2 += __shfl_down(d2, off, 64);
        if (lane == 0) {
            atomicAdd(sum_sq, d2);
            atomicAdd(&counts[best], 1);
            out[IDX_OFF + n] = (float)best;
        }
    }
}

__global__ __launch_bounds__(1024) void finalize_kernel(
    const int* __restrict__ counts, const double* __restrict__ sum_sq,
    float* __restrict__ out) {
    __shared__ double red[1024];
    int e = threadIdx.x;
    double em = (double)counts[e] / (double)N_TOK;
    red[e] = -em * log(em + 1e-10);
    __syncthreads();
    for (int s = 512; s > 0; s >>= 1) {
        if (e < s) red[e] += red[e + s];
        __syncthreads();
    }
    if (e == 0) {
        double usage = red[0];
        double mse = sum_sq[0] / (double)((size_t)N_TOK * E_DIM);
        out[LOSS_OFF] = (float)((1.0 + BETA) * mse + 0.01 * usage);
        out[PERP_OFF] = (float)exp(usage);
    }
}

extern "C" void kernel_launch(void* const* d_in, const int* in_sizes, int n_in,
                              void* d_out, int out_size, void* d_ws, size_t ws_size,
                              hipStream_t stream) {
    const float* z  = (const float*)d_in[0];
    const float* cb = (const float*)d_in[1];
    float* out = (float*)d_out;

    float*          c2     = (float*)((char*)d_ws + WS_C2);
    int*            counts = (int*)((char*)d_ws + WS_CNT);
    double*         sum_sq = (double*)((char*)d_ws + WS_SSQ);
    int*            wlc    = (int*)((char*)d_ws + WS_WLC);
    unsigned short* c2h    = (unsigned short*)((char*)d_ws + WS_C2H);
    unsigned short* fh     = (unsigned short*)((char*)d_ws + WS_FH);
    u64*            wlA    = (u64*)((char*)d_ws + WS_WLA);
    int*            wlB    = (int*)((char*)d_ws + WS_WLB);
    u64*            keysB  = (u64*)((char*)d_ws + WS_KEYSB);

    // u''-space margin: 0.07 validated rounds 1-3; +1e-3 covers the 64-ULP
    // key quantization in the v2/v3 comparisons.
    float margin_u = (ws_size >= (size_t)(WS_KEYSB + 8 * WLCAP_B)) ? 0.071f : 0.0f;

    frag_kernel<<<256, 256, 0, stream>>>(cb, fh, keysB, c2, c2h, counts, wlc,
                                         sum_sq);
    vq_main<<<256, 1024, 0, stream>>>(z, cb, c2, c2h, fh, counts, sum_sq,
                                      wlc, wlA, wlB, margin_u, out);
    cand_fix<<<128, 256, 0, stream>>>(z, cb, c2, wlA, wlc, counts, sum_sq, out);
    fixup_scan<<<4096, 64, 0, stream>>>(z, cb, c2, wlB, wlc, keysB);
    fixup_apply<<<256, 256, 0, stream>>>(z, cb, wlB, wlc, keysB, counts,
                                         sum_sq, out);
    finalize_kernel<<<1, 1024, 0, stream>>>(counts, sum_sq, out);
}